// Round 9
// baseline (153.861 us; speedup 1.0000x reference)
//
#include <hip/hip_runtime.h>
#include <hip/hip_bf16.h>
#include <cstdint>
#include <cstddef>

typedef __attribute__((ext_vector_type(8))) short short8;
typedef __attribute__((ext_vector_type(4))) float f32x4;

static constexpr int M_TOT = 31744;
static constexpr int N_TOT = 1152;
static constexpr int K_TOT = 768;
static constexpr long W_ELEMS = (long)N_TOT * K_TOT;   // 884736
static constexpr int CYC_ROWS = 3968;                  // one ragged cycle (4 images)

__device__ __forceinline__ unsigned short f2bf(float f) {
  unsigned int u = __float_as_uint(f);
  u += 0x7FFFu + ((u >> 16) & 1u);   // round-to-nearest-even
  return (unsigned short)(u >> 16);
}
__device__ __forceinline__ float bf2f(unsigned short u) {
  return __uint_as_float((unsigned int)u << 16);
}
__device__ __forceinline__ unsigned int cvtpk(float lo, float hi) {
  unsigned int r;
  asm("v_cvt_pk_bf16_f32 %0, %1, %2" : "=v"(r) : "v"(lo), "v"(hi));
  return r;
}

// ---------------- prep: W fp32->bf16 (blocks 0..431) + pos table (blocks 432..2663) ----
// tab[rem,d] = bf16(bias[d] + bilinear(pos)[rem,d]); shapes repeat 8x -> 3968 rows.
__global__ void prep_kernel(const float* __restrict__ W, const float* __restrict__ pos,
                            const float* __restrict__ bias,
                            unsigned short* __restrict__ Wbf, unsigned short* __restrict__ tab) {
  const int b = blockIdx.x;
  if (b < 432) {   // 432*256*8 = 884736 = W_ELEMS exactly
    const long i = ((long)b * 256 + threadIdx.x) * 8;
    float4 v0 = *(const float4*)(W + i);
    float4 v1 = *(const float4*)(W + i + 4);
    short8 o;
    o[0] = (short)f2bf(v0.x); o[1] = (short)f2bf(v0.y);
    o[2] = (short)f2bf(v0.z); o[3] = (short)f2bf(v0.w);
    o[4] = (short)f2bf(v1.x); o[5] = (short)f2bf(v1.y);
    o[6] = (short)f2bf(v1.z); o[7] = (short)f2bf(v1.w);
    *(short8*)(Wbf + i) = o;
    return;
  }
  const int t = (b - 432) * 256 + threadIdx.x;   // 571392 = 3968 * 144
  const int row = t / 144;                        // rem in [0,3968)
  const int dc = (t - row * 144) * 8;             // d chunk base

  int rr, cc; float sy, sx;
  if (row < 1024)      { rr = row >> 5; cc = row & 31; sy = 0.5f;         sx = 0.5f; }
  else if (row < 2048) { const int li = row - 1024; rr = li >> 6; cc = li & 63; sy = 1.0f; sx = 0.25f; }
  else if (row < 3008) { const int li = row - 2048; rr = li / 40; cc = li - rr * 40; sy = 16.0f / 24.0f; sx = 0.4f; }
  else                 { const int li = row - 3008; rr = li / 24; cc = li - rr * 24; sy = 0.4f; sx = 16.0f / 24.0f; }
  // half-pixel centers, clamped (upsampling => antialias identity, edge renorm == clamp)
  float yc = fminf(fmaxf(((float)rr + 0.5f) * sy - 0.5f, 0.0f), 15.0f);
  const int y0 = (int)yc; const float fy = yc - (float)y0;
  const int y1 = y0 < 15 ? y0 + 1 : 15;
  float xc = fminf(fmaxf(((float)cc + 0.5f) * sx - 0.5f, 0.0f), 15.0f);
  const int x0 = (int)xc; const float fx = xc - (float)x0;
  const int x1 = x0 < 15 ? x0 + 1 : 15;
  const float w11 = fy * fx;
  const float w10 = fy - w11;
  const float w01 = fx - w11;
  const float w00 = 1.0f - fy - fx + w11;
  const float* p00 = pos + (size_t)(y0 * 16 + x0) * 1152 + dc;
  const float* p01 = pos + (size_t)(y0 * 16 + x1) * 1152 + dc;
  const float* p10 = pos + (size_t)(y1 * 16 + x0) * 1152 + dc;
  const float* p11 = pos + (size_t)(y1 * 16 + x1) * 1152 + dc;
  const float* bi  = bias + dc;
  short8 o;
#pragma unroll
  for (int j = 0; j < 8; ++j) {
    const float v = bi[j] + w00 * p00[j] + w01 * p01[j] + w10 * p10[j] + w11 * p11[j];
    o[j] = (short)f2bf(v);
  }
  *(short8*)(tab + (size_t)row * 1152 + dc) = o;
}

// ---------------- fused GEMM: A reg-staged fp32->bf16->LDS, B direct global->regs ----
// 128x128 tile, BK=64, 256 threads = 4 waves (2x2), wave-tile 64x64, 12 K-tiles.
// No global_load_lds anywhere (ablation). A: issue 8 float4 loads for t+1 before
// COMPUTE(t) (T14), convert+ds_write after. B-frags load straight from L2-resident
// Wbf in MFMA layout (no LDS, no staging barrier). One __syncthreads per K-tile.
// LDS 2 x 16 KB = 32 KB.
__global__ __launch_bounds__(256, 3) void gemm_kernel(
    const float* __restrict__ Afp, const unsigned short* __restrict__ Wbf,
    const unsigned short* __restrict__ tab, float* __restrict__ outp) {
  __shared__ __attribute__((aligned(16))) unsigned short As[2][128 * 64];  // 2 x 16 KB

  // XCD-bijective swizzle: 2232 tiles = 8 XCDs * 279.
  const int bid = blockIdx.x;
  const int tile = (bid & 7) * 279 + (bid >> 3);
  const int tm = tile / 9, tn = tile % 9;   // 248 x 9 tiles of 128x128
  const int m0 = tm * 128, n0 = tn * 128;

  const int tid = threadIdx.x;
  const int wid = tid >> 6, lane = tid & 63;
  const int wr = wid >> 1, wc = wid & 1;    // 2x2 waves, 64x64 each
  const int rb = wid * 32;                  // this wave's A staging row base
  const int kg = lane >> 4, l15 = lane & 15;
  // A staging lane map: row = rb + c*8 + (lane>>3); fp32 col-octet = (lane&7)*8.
  // ds_write chunk swizzle key = (row&7) = (lane>>3)  (rb, c*8 are multiples of 8)
  const int dsw = (((lane & 7) ^ (lane >> 3)) << 4);   // byte offset of 16B chunk

  f32x4 acc[4][4] = {};
  float4 f0[4], f1[4];      // in-flight A fp32 (held across COMPUTE)
  short8 fbt[4][2];         // B fragments, direct from global

#define ALOAD(kt)                                                                \
  _Pragma("unroll") for (int c = 0; c < 4; ++c) {                                \
    const float* s_ = Afp + (size_t)(m0 + rb + c * 8 + (lane >> 3)) * K_TOT +    \
                      (kt) * 64 + (lane & 7) * 8;                                \
    f0[c] = *(const float4*)s_;                                                  \
    f1[c] = *(const float4*)(s_ + 4);                                            \
  }

#define AWRITE(q_)                                                               \
  _Pragma("unroll") for (int c = 0; c < 4; ++c) {                                \
    int4 w_;                                                                     \
    w_.x = (int)cvtpk(f0[c].x, f0[c].y);                                         \
    w_.y = (int)cvtpk(f0[c].z, f0[c].w);                                         \
    w_.z = (int)cvtpk(f1[c].x, f1[c].y);                                         \
    w_.w = (int)cvtpk(f1[c].z, f1[c].w);                                         \
    *(int4*)((char*)As[q_] + (rb + c * 8 + (lane >> 3)) * 128 + dsw) = w_;       \
  }

#define BLOAD(kt)                                                                \
  _Pragma("unroll") for (int n = 0; n < 4; ++n) {                                \
    const unsigned short* s_ = Wbf + (size_t)(n0 + wc * 64 + n * 16 + l15) *     \
                               K_TOT + (kt) * 64 + kg * 8;                       \
    fbt[n][0] = *(const short8*)s_;                                              \
    fbt[n][1] = *(const short8*)(s_ + 32);                                       \
  }

#define COMPUTE(p_)                                                              \
  { __builtin_amdgcn_s_setprio(1);                                               \
    _Pragma("unroll") for (int kk = 0; kk < 2; ++kk) {                           \
      short8 fa[4];                                                              \
      _Pragma("unroll") for (int m = 0; m < 4; ++m) {                            \
        const int arow = wr * 64 + m * 16 + l15;                                 \
        fa[m] = *(const short8*)((const char*)As[p_] + arow * 128 +              \
                                 (((kk * 4 + kg) ^ (arow & 7)) << 4));           \
      }                                                                          \
      _Pragma("unroll") for (int m = 0; m < 4; ++m)                              \
        _Pragma("unroll") for (int n = 0; n < 4; ++n)                            \
          acc[m][n] = __builtin_amdgcn_mfma_f32_16x16x32_bf16(                   \
              fa[m], fbt[n][kk], acc[m][n], 0, 0, 0);                            \
    }                                                                            \
    __builtin_amdgcn_s_setprio(0); }

  // prologue: tile 0 -> As[0]
  ALOAD(0)
  AWRITE(0)
  __syncthreads();

#pragma unroll
  for (int t = 0; t < 12; ++t) {
    if (t < 11) ALOAD(t + 1)            // issue early: lands under COMPUTE (T14)
    BLOAD(t)                            // L2-hit B frags, direct to regs
    __builtin_amdgcn_sched_barrier(0);  // pin load issue above COMPUTE
    COMPUTE(t & 1)
    if (t < 11) {
      AWRITE((t & 1) ^ 1)               // cvt (auto vmcnt wait) + ds_write next buf
      __syncthreads();
    }
  }

#undef ALOAD
#undef AWRITE
#undef BLOAD
#undef COMPUTE

  // ---------------- epilogue (r5-verified): out = acc + tab[s % 3968, d] ----------
  const int s_base = m0 + wr * 64 + ((lane >> 4) << 2);  // + m*16 + r
  const int rem_base = s_base % CYC_ROWS;
  const int d_base = n0 + wc * 64 + l15;                 // + n*16

#pragma unroll
  for (int m = 0; m < 4; ++m) {
#pragma unroll
    for (int r = 0; r < 4; ++r) {
      const int off = m * 16 + r;
      int rem = rem_base + off;
      if (rem >= CYC_ROWS) rem -= CYC_ROWS;
      const unsigned short* trow = tab + (size_t)rem * 1152 + d_base;
      float* orow = outp + (size_t)(s_base + off) * 1152 + d_base;
#pragma unroll
      for (int n = 0; n < 4; ++n)
        orow[n * 16] = acc[m][n][r] + bf2f(trow[n * 16]);
    }
  }
}

extern "C" void kernel_launch(void* const* d_in, const int* in_sizes, int n_in,
                              void* d_out, int out_size, void* d_ws, size_t ws_size,
                              hipStream_t stream) {
  const float* A    = (const float*)d_in[0];  // seq_patches [31744,768] fp32
  const float* W    = (const float*)d_in[1];  // w [1152,768] fp32
  const float* bias = (const float*)d_in[2];  // b [1152]
  const float* pos  = (const float*)d_in[3];  // pos_emb [256,1152]
  unsigned short* Wbf = (unsigned short*)d_ws;            // 1.77 MB
  unsigned short* tab = Wbf + W_ELEMS;                    // +9.14 MB (3968*1152)
  float* outp = (float*)d_out;

  prep_kernel<<<2664, 256, 0, stream>>>(W, pos, bias, Wbf, tab);
  gemm_kernel<<<2232, 256, 0, stream>>>(A, Wbf, tab, outp);
}